// Round 3
// baseline (26699.936 us; speedup 1.0000x reference)
//
#include <hip/hip_runtime.h>
#include <cstdint>
#include <cstddef>

#define T_SEQ 1024
#define BATCH 64
#define DIM   256
#define HID   256
#define NG    (4*HID)   // 1024 gate columns, j = g*256 + r, g in {f,i,g~,o}

typedef _Float16 h2v __attribute__((ext_vector_type(2)));
union U16 { uint4 u; h2v h[4]; };

__device__ __forceinline__ float sigm_f(float x) {
    return 1.0f / (1.0f + __expf(-x));
}
__device__ __forceinline__ float tanh_f(float x) {
    x = fminf(fmaxf(x, -15.0f), 15.0f);   // avoid inf/inf
    float e = __expf(2.0f * x);
    return (e - 1.0f) / (e + 1.0f);
}

// ---------------- phase 0: repack weights, zero state/flags -------------------
// wx4[(k*256 + r)*4 + g] = W_g[r][k]                      (x part, fp32)
// wzs slab layout for WG s (s = unit>>6):
//   wzs[((s*32 + (k>>3))*256 + (g*64 + (r&63)))*8 + (k&7)] = fp16(W_g[r][256+k])
// bias4[r*4+g] = b_g[r]
__global__ void pack_kernel(const float* __restrict__ Wf, const float* __restrict__ bf,
                            const float* __restrict__ Wi, const float* __restrict__ bi,
                            const float* __restrict__ Wg, const float* __restrict__ bg,
                            const float* __restrict__ Wo, const float* __restrict__ bo,
                            float* __restrict__ wx4, _Float16* __restrict__ wzs,
                            float* __restrict__ bias4,
                            float* __restrict__ hstate, float* __restrict__ cstate,
                            int* __restrict__ flags) {
    int k = blockIdx.x;          // 0..255
    int j = threadIdx.x;         // 0..1023
    int r = j & 255, g = j >> 8;
    const float* W  = (g == 0) ? Wf : (g == 1) ? Wi : (g == 2) ? Wg : Wo;
    const float* bb = (g == 0) ? bf : (g == 1) ? bi : (g == 2) ? bg : bo;
    wx4[((size_t)k * 256 + r) * 4 + g] = W[(size_t)r * 512 + k];
    int s = r >> 6;
    wzs[(((size_t)(s * 32 + (k >> 3))) * 256 + (g * 64 + (r & 63))) * 8 + (k & 7)] =
        (_Float16)W[(size_t)r * 512 + 256 + k];
    if (k == 0) bias4[r * 4 + g] = bb[r];
    if (k < 64 && g == 0) hstate[k * 256 + r] = 0.0f;
    if (k < 64 && g == 1) cstate[k * 256 + r] = 0.0f;
    if (k >= 1 && k <= 4) flags[(k - 1) * 1024 + j] = 0;   // 16 KB of flags
}

// ---------------- phase 1: Xproj[row][j] = x_row . Wx_col_j + bias ------------
__global__ __launch_bounds__(256) void xproj_kernel(
        const float* __restrict__ X, const float* __restrict__ wx4,
        const float* __restrict__ bias4, float* __restrict__ xp) {
    __shared__ __align__(16) float xl[256 * 20];   // [k][row] padded
    int tid = threadIdx.x;
    int R0 = blockIdx.x * 16;
    #pragma unroll
    for (int i = 0; i < 16; ++i)
        xl[tid * 20 + i] = X[(size_t)(R0 + i) * DIM + tid];
    __syncthreads();

    float4 bv = ((const float4*)bias4)[tid];
    float acc[16][4];
    #pragma unroll
    for (int i = 0; i < 16; ++i) {
        acc[i][0] = bv.x; acc[i][1] = bv.y; acc[i][2] = bv.z; acc[i][3] = bv.w;
    }
    const float4* __restrict__ wp = (const float4*)wx4 + tid;
    #pragma unroll 2
    for (int k = 0; k < 256; ++k) {
        float4 w  = wp[k << 8];
        float4 xa = *(const float4*)&xl[k * 20 + 0];
        float4 xb = *(const float4*)&xl[k * 20 + 4];
        float4 xc = *(const float4*)&xl[k * 20 + 8];
        float4 xd = *(const float4*)&xl[k * 20 + 12];
        float xr[16] = {xa.x, xa.y, xa.z, xa.w, xb.x, xb.y, xb.z, xb.w,
                        xc.x, xc.y, xc.z, xc.w, xd.x, xd.y, xd.z, xd.w};
        #pragma unroll
        for (int i = 0; i < 16; ++i) {
            acc[i][0] = fmaf(xr[i], w.x, acc[i][0]);
            acc[i][1] = fmaf(xr[i], w.y, acc[i][1]);
            acc[i][2] = fmaf(xr[i], w.z, acc[i][2]);
            acc[i][3] = fmaf(xr[i], w.w, acc[i][3]);
        }
    }
    #pragma unroll
    for (int i = 0; i < 16; ++i)
        #pragma unroll
        for (int g = 0; g < 4; ++g)
            xp[(size_t)(R0 + i) * NG + g * HID + tid] = acc[i][g];
}

// ---------------- phase 2: recurrence, 4 WGs per batch element ----------------
// WG (s,b), blockIdx = s*64 + b  (partners share XCD since 64%8==0).
// Thread t (0..255): gate = t>>6 (wave-uniform), lane = t&63,
// column j = gate*256 + s*64 + lane. Weight slab (128 KB) lives in LDS.
// Per step: matvec from LDS; gates -> c,h for own 64 units; h-slice exchange
// via L2 with parity double-buffer + monotone flags.
__global__ __launch_bounds__(256, 1) void lstm_step_kernel(
        const float* __restrict__ xp, const _Float16* __restrict__ wzs,
        float* __restrict__ hstate, float* __restrict__ cstate,
        float* __restrict__ hx, int* __restrict__ flags,
        float* __restrict__ out, int t0, int Tc) {
    __shared__ __align__(16) _Float16 wl[32 * 256 * 8];  // 128 KB weight slab
    __shared__ __align__(16) _Float16 hl[HID];           // full h, fp16
    __shared__ float gl[256];                            // gate outputs this WG
    int s = blockIdx.x >> 6, b = blockIdx.x & 63;
    int t = threadIdx.x;
    int gate = t >> 6, lane = t & 63;

    // load weight slab (global -> LDS), coalesced uint4
    {
        const uint4* src = (const uint4*)(wzs + (size_t)s * 65536);
        uint4* dst = (uint4*)wl;
        #pragma unroll
        for (int i = 0; i < 32; ++i)
            dst[i * 256 + t] = src[i * 256 + t];
    }
    // init state
    hl[t] = (_Float16)hstate[b * HID + t];
    float creg = 0.0f, hreg = 0.0f;
    if (t < 64) {
        creg = cstate[b * HID + s * 64 + t];
        hreg = hstate[b * HID + s * 64 + t];
    }
    __syncthreads();

    int myflag = (b * 4 + s) * 16;
    // partner slice ids for waves 1..3: q = gate-1, s2 = q + (q >= s)
    int s2 = (gate - 1) + ((gate - 1) >= s ? 1 : 0);   // valid for gate>=1

    for (int tt = 0; tt < Tc; ++tt) {
        int step = t0 + tt + 1;
        int par  = step & 1;
        // ---- matvec: column j = gate*256 + s*64 + lane ----
        float acc = xp[((size_t)tt * BATCH + b) * NG + gate * 256 + s * 64 + lane];
        float s0 = 0.f, s1 = 0.f, s2a = 0.f, s3 = 0.f;
        #pragma unroll 8
        for (int k8 = 0; k8 < 32; ++k8) {
            U16 w, h;
            w.u = *(const uint4*)&wl[(size_t)(k8 * 256 + t) * 8];
            h.u = *(const uint4*)&hl[k8 * 8];
            s0  = __builtin_amdgcn_fdot2(w.h[0], h.h[0], s0, false);
            s1  = __builtin_amdgcn_fdot2(w.h[1], h.h[1], s1, false);
            s2a = __builtin_amdgcn_fdot2(w.h[2], h.h[2], s2a, false);
            s3  = __builtin_amdgcn_fdot2(w.h[3], h.h[3], s3, false);
        }
        acc += (s0 + s1) + (s2a + s3);
        gl[t] = (gate == 2) ? tanh_f(acc) : sigm_f(acc);   // wave-uniform branch
        __syncthreads();
        // ---- elementwise update for own 64 units ----
        if (t < 64) {
            float f  = gl[t];
            float ii = gl[64 + t];
            float gg = gl[128 + t];
            float o  = gl[192 + t];
            float c  = fmaf(f, creg, ii * gg);
            creg = c;
            float h = o * tanh_f(c);
            hreg = h;
            out[((size_t)(t0 + tt) * BATCH + b) * HID + s * 64 + t] = h;
            hl[s * 64 + t] = (_Float16)h;   // own slice (matvec reads done: barrier above)
            __hip_atomic_store(&hx[(par * 256 + b * 4 + s) * 64 + t], h,
                               __ATOMIC_RELAXED, __HIP_MEMORY_SCOPE_AGENT);
        }
        __threadfence();
        __syncthreads();
        if (t == 0)
            __hip_atomic_store(&flags[myflag], step,
                               __ATOMIC_RELEASE, __HIP_MEMORY_SCOPE_AGENT);
        if (t >= 64) {
            const int* fp = &flags[(b * 4 + s2) * 16];
            while (__hip_atomic_load(fp, __ATOMIC_ACQUIRE, __HIP_MEMORY_SCOPE_AGENT) < step) {}
            float v = __hip_atomic_load(&hx[(par * 256 + b * 4 + s2) * 64 + lane],
                                        __ATOMIC_RELAXED, __HIP_MEMORY_SCOPE_AGENT);
            hl[s2 * 64 + lane] = (_Float16)v;
        }
        __syncthreads();   // hl(t+1) complete
    }
    if (t < 64) {
        cstate[b * HID + s * 64 + t] = creg;
        hstate[b * HID + s * 64 + t] = hreg;
    }
}

// ---------------- tail: final hx, cx ------------------------------------------
__global__ void tail_kernel(const float* __restrict__ hstate,
                            const float* __restrict__ cstate, float* __restrict__ out) {
    int b = blockIdx.x, r = threadIdx.x;
    size_t base = (size_t)T_SEQ * BATCH * HID;
    out[base + b * HID + r] = hstate[b * HID + r];
    out[base + (size_t)BATCH * HID + b * HID + r] = cstate[b * HID + r];
}

extern "C" void kernel_launch(void* const* d_in, const int* in_sizes, int n_in,
                              void* d_out, int out_size, void* d_ws, size_t ws_size,
                              hipStream_t stream) {
    (void)in_sizes; (void)n_in; (void)out_size;
    const float* X  = (const float*)d_in[0];
    const float* Wf = (const float*)d_in[1];
    const float* bf = (const float*)d_in[2];
    const float* Wi = (const float*)d_in[3];
    const float* bi = (const float*)d_in[4];
    const float* Wg = (const float*)d_in[5];
    const float* bg = (const float*)d_in[6];
    const float* Wo = (const float*)d_in[7];
    const float* bo = (const float*)d_in[8];
    float* out = (float*)d_out;
    char*  ws  = (char*)d_ws;

    const size_t MB = 1 << 20, KB = 1 << 10;
    float*    wx4    = (float*)(ws);                          // 1 MB
    _Float16* wzs    = (_Float16*)(ws + MB);                  // 512 KB
    float*    bias4  = (float*)(ws + MB + 512 * KB);          // 4 KB (pad 64K)
    float*    hstate = (float*)(ws + MB + 576 * KB);          // 64 KB
    float*    cstate = (float*)(ws + MB + 640 * KB);          // 64 KB
    float*    hx     = (float*)(ws + MB + 704 * KB);          // 128 KB (2 x 256 x 64 f32)
    int*      flags  = (int*)  (ws + MB + 832 * KB);          // 16 KB
    float*    xproj  = (float*)(ws + 2 * MB);

    size_t fixed = 2 * MB;
    int Tc = 1024;
    while (Tc > 16 && fixed + (size_t)Tc * BATCH * NG * 4 > ws_size) Tc >>= 1;

    pack_kernel<<<256, 1024, 0, stream>>>(Wf, bf, Wi, bi, Wg, bg, Wo, bo,
                                          wx4, wzs, bias4, hstate, cstate, flags);
    for (int t0 = 0; t0 < T_SEQ; t0 += Tc) {
        xproj_kernel<<<Tc * BATCH / 16, 256, 0, stream>>>(
            X + (size_t)t0 * BATCH * DIM, wx4, bias4, xproj);
        lstm_step_kernel<<<4 * BATCH, 256, 0, stream>>>(
            xproj, wzs, hstate, cstate, hx, flags, out, t0, Tc);
    }
    tail_kernel<<<BATCH, HID, 0, stream>>>(hstate, cstate, out);
}

// Round 4
// 3839.646 us; speedup vs baseline: 6.9537x; 6.9537x over previous
//
#include <hip/hip_runtime.h>
#include <cstdint>
#include <cstddef>

#define T_SEQ 1024
#define BATCH 64
#define DIM   256
#define HID   256
#define NG    (4*HID)   // 1024 gate columns, j = g*256 + r, g in {f,i,g~,o}
#define KL8   8         // k8-slices of weights resident in LDS (8 x 16 KB = 128 KB)

typedef _Float16 h2v __attribute__((ext_vector_type(2)));
union U16 { uint4 u; h2v h[4]; };

__device__ __forceinline__ float sigm_f(float x) {
    return 1.0f / (1.0f + __expf(-x));
}
__device__ __forceinline__ float tanh_f(float x) {
    x = fminf(fmaxf(x, -15.0f), 15.0f);   // avoid inf/inf
    float e = __expf(2.0f * x);
    return (e - 1.0f) / (e + 1.0f);
}

// ---------------- phase 0: repack weights, zero state -------------------------
// wx4[(k*256 + r)*4 + g] = W_g[r][k]                     (x part, fp32)
// wzh[((k>>3)*1024 + j)*8 + (k&7)] = fp16(W_g[r][256+k]) (h part, fp16 k-packs of 8)
// bias4[r*4+g] = b_g[r]
__global__ void pack_kernel(const float* __restrict__ Wf, const float* __restrict__ bf,
                            const float* __restrict__ Wi, const float* __restrict__ bi,
                            const float* __restrict__ Wg, const float* __restrict__ bg,
                            const float* __restrict__ Wo, const float* __restrict__ bo,
                            float* __restrict__ wx4, _Float16* __restrict__ wzh,
                            float* __restrict__ bias4,
                            float* __restrict__ hstate, float* __restrict__ cstate) {
    int k = blockIdx.x;          // 0..255
    int j = threadIdx.x;         // 0..1023
    int r = j & 255, g = j >> 8;
    const float* W  = (g == 0) ? Wf : (g == 1) ? Wi : (g == 2) ? Wg : Wo;
    const float* bb = (g == 0) ? bf : (g == 1) ? bi : (g == 2) ? bg : bo;
    wx4[((size_t)k * 256 + r) * 4 + g] = W[(size_t)r * 512 + k];
    wzh[(((size_t)(k >> 3)) * 1024 + j) * 8 + (k & 7)] = (_Float16)W[(size_t)r * 512 + 256 + k];
    if (k == 0) bias4[r * 4 + g] = bb[r];
    if (k < 64 && g == 0) hstate[k * 256 + r] = 0.0f;
    if (k < 64 && g == 1) cstate[k * 256 + r] = 0.0f;
}

// ---------------- phase 1: Xproj[row][j] = x_row . Wx_col_j + bias ------------
__global__ __launch_bounds__(256) void xproj_kernel(
        const float* __restrict__ X, const float* __restrict__ wx4,
        const float* __restrict__ bias4, float* __restrict__ xp) {
    __shared__ __align__(16) float xl[256 * 20];   // [k][row] padded
    int tid = threadIdx.x;
    int R0 = blockIdx.x * 16;
    #pragma unroll
    for (int i = 0; i < 16; ++i)
        xl[tid * 20 + i] = X[(size_t)(R0 + i) * DIM + tid];
    __syncthreads();

    float4 bv = ((const float4*)bias4)[tid];
    float acc[16][4];
    #pragma unroll
    for (int i = 0; i < 16; ++i) {
        acc[i][0] = bv.x; acc[i][1] = bv.y; acc[i][2] = bv.z; acc[i][3] = bv.w;
    }
    const float4* __restrict__ wp = (const float4*)wx4 + tid;
    #pragma unroll 2
    for (int k = 0; k < 256; ++k) {
        float4 w  = wp[k << 8];
        float4 xa = *(const float4*)&xl[k * 20 + 0];
        float4 xb = *(const float4*)&xl[k * 20 + 4];
        float4 xc = *(const float4*)&xl[k * 20 + 8];
        float4 xd = *(const float4*)&xl[k * 20 + 12];
        float xr[16] = {xa.x, xa.y, xa.z, xa.w, xb.x, xb.y, xb.z, xb.w,
                        xc.x, xc.y, xc.z, xc.w, xd.x, xd.y, xd.z, xd.w};
        #pragma unroll
        for (int i = 0; i < 16; ++i) {
            acc[i][0] = fmaf(xr[i], w.x, acc[i][0]);
            acc[i][1] = fmaf(xr[i], w.y, acc[i][1]);
            acc[i][2] = fmaf(xr[i], w.z, acc[i][2]);
            acc[i][3] = fmaf(xr[i], w.w, acc[i][3]);
        }
    }
    #pragma unroll
    for (int i = 0; i < 16; ++i)
        #pragma unroll
        for (int g = 0; g < 4; ++g)
            xp[(size_t)(R0 + i) * NG + g * HID + tid] = acc[i][g];
}

// ---------------- phase 2: sequential recurrence, 1 WG per batch element -----
// fp16 weights + fp16 h, fp32 accumulate via v_dot2_f32_f16.
// First KL8*8 of the 256 k-values come from a 128 KB LDS-resident slab
// (loaded once per dispatch); the remaining (32-KL8)*16 KB stream from L2.
__global__ __launch_bounds__(1024, 1) void lstm_step_kernel(
        const float* __restrict__ xp, const _Float16* __restrict__ wzh,
        float* __restrict__ hstate, float* __restrict__ cstate,
        float* __restrict__ out, int t0, int Tc) {
    __shared__ __align__(16) _Float16 wl[KL8 * 1024 * 8];   // 128 KB weight slab
    __shared__ __align__(16) _Float16 hl2[HID];             // fp16 h
    __shared__ float cl[HID];
    __shared__ float gl[NG];
    int b = blockIdx.x, j = threadIdx.x;
    int g = j >> 8;

    // stage first KL8 k8-slices into LDS (coalesced uint4, 8 per thread)
    {
        const uint4* src = (const uint4*)wzh;
        uint4* dst = (uint4*)wl;
        #pragma unroll
        for (int i = 0; i < KL8; ++i)
            dst[i * 1024 + j] = src[i * 1024 + j];
    }
    if (j < HID) {
        cl[j]  = cstate[b * HID + j];
        hl2[j] = (_Float16)hstate[b * HID + j];
    }
    __syncthreads();

    const uint4* __restrict__ wp = (const uint4*)wzh + (size_t)KL8 * 1024 + j;
    for (int tt = 0; tt < Tc; ++tt) {
        float acc = xp[((size_t)tt * BATCH + b) * NG + j];
        float s0 = 0.f, s1 = 0.f, s2 = 0.f, s3 = 0.f;
        // LDS-resident part
        #pragma unroll
        for (int k8 = 0; k8 < KL8; ++k8) {
            U16 w, h;
            w.u = *(const uint4*)&wl[(size_t)(k8 * 1024 + j) * 8];
            h.u = *(const uint4*)&hl2[k8 * 8];
            s0 = __builtin_amdgcn_fdot2(w.h[0], h.h[0], s0, false);
            s1 = __builtin_amdgcn_fdot2(w.h[1], h.h[1], s1, false);
            s2 = __builtin_amdgcn_fdot2(w.h[2], h.h[2], s2, false);
            s3 = __builtin_amdgcn_fdot2(w.h[3], h.h[3], s3, false);
        }
        // L2-streamed part
        #pragma unroll 8
        for (int k8 = 0; k8 < 32 - KL8; ++k8) {
            U16 w, h;
            w.u = wp[(size_t)k8 * 1024];
            h.u = *(const uint4*)&hl2[(KL8 + k8) * 8];
            s0 = __builtin_amdgcn_fdot2(w.h[0], h.h[0], s0, false);
            s1 = __builtin_amdgcn_fdot2(w.h[1], h.h[1], s1, false);
            s2 = __builtin_amdgcn_fdot2(w.h[2], h.h[2], s2, false);
            s3 = __builtin_amdgcn_fdot2(w.h[3], h.h[3], s3, false);
        }
        acc += (s0 + s1) + (s2 + s3);
        gl[j] = (g == 2) ? tanh_f(acc) : sigm_f(acc);
        __syncthreads();
        if (j < HID) {
            float f  = gl[j];
            float ii = gl[HID + j];
            float gg = gl[2 * HID + j];
            float o  = gl[3 * HID + j];
            float c  = fmaf(f, cl[j], ii * gg);
            cl[j] = c;
            float h = o * tanh_f(c);
            hl2[j] = (_Float16)h;
            out[((size_t)(t0 + tt) * BATCH + b) * HID + j] = h;
        }
        __syncthreads();
    }
    if (j < HID) {
        hstate[b * HID + j] = (float)hl2[j];
        cstate[b * HID + j] = cl[j];
    }
}

// ---------------- tail: final hx, cx ------------------------------------------
__global__ void tail_kernel(const float* __restrict__ hstate,
                            const float* __restrict__ cstate, float* __restrict__ out) {
    int b = blockIdx.x, r = threadIdx.x;
    size_t base = (size_t)T_SEQ * BATCH * HID;
    out[base + b * HID + r] = hstate[b * HID + r];
    out[base + (size_t)BATCH * HID + b * HID + r] = cstate[b * HID + r];
}

extern "C" void kernel_launch(void* const* d_in, const int* in_sizes, int n_in,
                              void* d_out, int out_size, void* d_ws, size_t ws_size,
                              hipStream_t stream) {
    (void)in_sizes; (void)n_in; (void)out_size;
    const float* X  = (const float*)d_in[0];
    const float* Wf = (const float*)d_in[1];
    const float* bf = (const float*)d_in[2];
    const float* Wi = (const float*)d_in[3];
    const float* bi = (const float*)d_in[4];
    const float* Wg = (const float*)d_in[5];
    const float* bg = (const float*)d_in[6];
    const float* Wo = (const float*)d_in[7];
    const float* bo = (const float*)d_in[8];
    float* out = (float*)d_out;
    char*  ws  = (char*)d_ws;

    const size_t MB = 1 << 20, KB = 1 << 10;
    float*    wx4    = (float*)(ws);                          // 1 MB
    _Float16* wzh    = (_Float16*)(ws + MB);                  // 512 KB
    float*    bias4  = (float*)(ws + MB + 512 * KB);          // 4 KB
    float*    hstate = (float*)(ws + MB + 576 * KB);          // 64 KB
    float*    cstate = (float*)(ws + MB + 640 * KB);          // 64 KB
    float*    xproj  = (float*)(ws + 2 * MB);

    size_t fixed = 2 * MB;
    int Tc = 1024;
    while (Tc > 16 && fixed + (size_t)Tc * BATCH * NG * 4 > ws_size) Tc >>= 1;

    pack_kernel<<<256, 1024, 0, stream>>>(Wf, bf, Wi, bi, Wg, bg, Wo, bo,
                                          wx4, wzh, bias4, hstate, cstate);
    for (int t0 = 0; t0 < T_SEQ; t0 += Tc) {
        xproj_kernel<<<Tc * BATCH / 16, 256, 0, stream>>>(
            X + (size_t)t0 * BATCH * DIM, wx4, bias4, xproj);
        lstm_step_kernel<<<BATCH, 1024, 0, stream>>>(
            xproj, wzh, hstate, cstate, out, t0, Tc);
    }
    tail_kernel<<<BATCH, HID, 0, stream>>>(hstate, cstate, out);
}

// Round 5
// 2742.445 us; speedup vs baseline: 9.7358x; 1.4001x over previous
//
#include <hip/hip_runtime.h>
#include <cstdint>
#include <cstddef>

#define T_SEQ 1024
#define BATCH 64
#define DIM   256
#define HID   256
#define NG    (4*HID)   // 1024 gate columns, j = g*256 + r, g in {f,i,g~,o}

typedef _Float16 h2v __attribute__((ext_vector_type(2)));
union U16 { uint4 u; h2v h[4]; };

__device__ __forceinline__ float sigm_f(float x) {
    return 1.0f / (1.0f + __expf(-x));
}
__device__ __forceinline__ float tanh_f(float x) {
    x = fminf(fmaxf(x, -15.0f), 15.0f);   // avoid inf/inf
    float e = __expf(2.0f * x);
    return (e - 1.0f) / (e + 1.0f);
}

// ---------------- phase 0: repack weights, zero state -------------------------
// wx4[(k*256 + r)*4 + g] = W_g[r][k]                     (x part, fp32)
// wzh[((k>>3)*1024 + j)*8 + (k&7)] = fp16(W_g[r][256+k]) (h part, fp16 k-packs of 8)
// bias4[r*4+g] = b_g[r]
__global__ void pack_kernel(const float* __restrict__ Wf, const float* __restrict__ bf,
                            const float* __restrict__ Wi, const float* __restrict__ bi,
                            const float* __restrict__ Wg, const float* __restrict__ bg,
                            const float* __restrict__ Wo, const float* __restrict__ bo,
                            float* __restrict__ wx4, _Float16* __restrict__ wzh,
                            float* __restrict__ bias4,
                            float* __restrict__ hstate, float* __restrict__ cstate) {
    int k = blockIdx.x;          // 0..255
    int j = threadIdx.x;         // 0..1023
    int r = j & 255, g = j >> 8;
    const float* W  = (g == 0) ? Wf : (g == 1) ? Wi : (g == 2) ? Wg : Wo;
    const float* bb = (g == 0) ? bf : (g == 1) ? bi : (g == 2) ? bg : bo;
    wx4[((size_t)k * 256 + r) * 4 + g] = W[(size_t)r * 512 + k];
    wzh[(((size_t)(k >> 3)) * 1024 + j) * 8 + (k & 7)] = (_Float16)W[(size_t)r * 512 + 256 + k];
    if (k == 0) bias4[r * 4 + g] = bb[r];
    if (k < 64 && g == 0) hstate[k * 256 + r] = 0.0f;
    if (k < 64 && g == 1) cstate[k * 256 + r] = 0.0f;
}

// ---------------- phase 1: Xproj[row][j] = x_row . Wx_col_j + bias ------------
__global__ __launch_bounds__(256) void xproj_kernel(
        const float* __restrict__ X, const float* __restrict__ wx4,
        const float* __restrict__ bias4, float* __restrict__ xp) {
    __shared__ __align__(16) float xl[256 * 20];   // [k][row] padded
    int tid = threadIdx.x;
    int R0 = blockIdx.x * 16;
    #pragma unroll
    for (int i = 0; i < 16; ++i)
        xl[tid * 20 + i] = X[(size_t)(R0 + i) * DIM + tid];
    __syncthreads();

    float4 bv = ((const float4*)bias4)[tid];
    float acc[16][4];
    #pragma unroll
    for (int i = 0; i < 16; ++i) {
        acc[i][0] = bv.x; acc[i][1] = bv.y; acc[i][2] = bv.z; acc[i][3] = bv.w;
    }
    const float4* __restrict__ wp = (const float4*)wx4 + tid;
    #pragma unroll 2
    for (int k = 0; k < 256; ++k) {
        float4 w  = wp[k << 8];
        float4 xa = *(const float4*)&xl[k * 20 + 0];
        float4 xb = *(const float4*)&xl[k * 20 + 4];
        float4 xc = *(const float4*)&xl[k * 20 + 8];
        float4 xd = *(const float4*)&xl[k * 20 + 12];
        float xr[16] = {xa.x, xa.y, xa.z, xa.w, xb.x, xb.y, xb.z, xb.w,
                        xc.x, xc.y, xc.z, xc.w, xd.x, xd.y, xd.z, xd.w};
        #pragma unroll
        for (int i = 0; i < 16; ++i) {
            acc[i][0] = fmaf(xr[i], w.x, acc[i][0]);
            acc[i][1] = fmaf(xr[i], w.y, acc[i][1]);
            acc[i][2] = fmaf(xr[i], w.z, acc[i][2]);
            acc[i][3] = fmaf(xr[i], w.w, acc[i][3]);
        }
    }
    #pragma unroll
    for (int i = 0; i < 16; ++i)
        #pragma unroll
        for (int g = 0; g < 4; ++g)
            xp[(size_t)(R0 + i) * NG + g * HID + tid] = acc[i][g];
}

// ---------------- phase 2: sequential recurrence, 1 WG per batch element -----
// 512 threads; thread t owns columns c0=t and c1=512+t.
// Weights: k in [0,64) -> 128 KB LDS slab; k in [64,256) -> 48 uint4 in VGPRs
// per thread (192 regs), loaded once. Zero per-step weight streaming.
// h fp16 in LDS (broadcast reads); c in thread-private fp32 regs.
__global__ __launch_bounds__(512, 2) void lstm_step_kernel(
        const float* __restrict__ xp, const _Float16* __restrict__ wzh,
        float* __restrict__ hstate, float* __restrict__ cstate,
        float* __restrict__ out, int t0, int Tc) {
    __shared__ __align__(16) _Float16 wl[8 * 1024 * 8];   // 128 KB: k8 = 0..7
    __shared__ __align__(16) _Float16 hl2[HID];           // fp16 h
    __shared__ float gl[NG];
    int t = threadIdx.x, b = blockIdx.x;
    int c0 = t, c1 = 512 + t;

    // stage k8 = 0..7 into LDS (8192 uint4 over 512 threads = 16 each)
    {
        const uint4* src = (const uint4*)wzh;
        uint4* dst = (uint4*)wl;
        #pragma unroll
        for (int i = 0; i < 16; ++i)
            dst[i * 512 + t] = src[i * 512 + t];
    }
    // register slab: k8 = 8..31 for columns c0 and c1 (48 uint4 = 192 VGPRs)
    uint4 wr0[24], wr1[24];
    {
        const uint4* src = (const uint4*)wzh;
        #pragma unroll
        for (int i = 0; i < 24; ++i) {
            wr0[i] = src[(size_t)(8 + i) * 1024 + c0];
            wr1[i] = src[(size_t)(8 + i) * 1024 + c1];
        }
    }
    float creg = 0.0f;
    if (t < 256) {
        creg   = cstate[b * HID + t];
        hl2[t] = (_Float16)hstate[b * HID + t];
    }
    __syncthreads();

    for (int tt = 0; tt < Tc; ++tt) {
        float a0 = xp[((size_t)tt * BATCH + b) * NG + c0];
        float a1 = xp[((size_t)tt * BATCH + b) * NG + c1];
        float s0a = 0.f, s0b = 0.f, s1a = 0.f, s1b = 0.f;
        // LDS-slab part: k8 = 0..7
        #pragma unroll
        for (int k8 = 0; k8 < 8; ++k8) {
            U16 h, w0, w1;
            h.u  = *(const uint4*)&hl2[k8 * 8];                      // broadcast
            w0.u = *(const uint4*)&wl[(size_t)(k8 * 1024 + c0) * 8];
            w1.u = *(const uint4*)&wl[(size_t)(k8 * 1024 + c1) * 8];
            s0a = __builtin_amdgcn_fdot2(w0.h[0], h.h[0], s0a, false);
            s0b = __builtin_amdgcn_fdot2(w0.h[1], h.h[1], s0b, false);
            s0a = __builtin_amdgcn_fdot2(w0.h[2], h.h[2], s0a, false);
            s0b = __builtin_amdgcn_fdot2(w0.h[3], h.h[3], s0b, false);
            s1a = __builtin_amdgcn_fdot2(w1.h[0], h.h[0], s1a, false);
            s1b = __builtin_amdgcn_fdot2(w1.h[1], h.h[1], s1b, false);
            s1a = __builtin_amdgcn_fdot2(w1.h[2], h.h[2], s1a, false);
            s1b = __builtin_amdgcn_fdot2(w1.h[3], h.h[3], s1b, false);
        }
        // register-slab part: k8 = 8..31
        #pragma unroll
        for (int i = 0; i < 24; ++i) {
            U16 h, w0, w1;
            h.u  = *(const uint4*)&hl2[(8 + i) * 8];                 // broadcast
            w0.u = wr0[i];
            w1.u = wr1[i];
            s0a = __builtin_amdgcn_fdot2(w0.h[0], h.h[0], s0a, false);
            s0b = __builtin_amdgcn_fdot2(w0.h[1], h.h[1], s0b, false);
            s0a = __builtin_amdgcn_fdot2(w0.h[2], h.h[2], s0a, false);
            s0b = __builtin_amdgcn_fdot2(w0.h[3], h.h[3], s0b, false);
            s1a = __builtin_amdgcn_fdot2(w1.h[0], h.h[0], s1a, false);
            s1b = __builtin_amdgcn_fdot2(w1.h[1], h.h[1], s1b, false);
            s1a = __builtin_amdgcn_fdot2(w1.h[2], h.h[2], s1a, false);
            s1b = __builtin_amdgcn_fdot2(w1.h[3], h.h[3], s1b, false);
        }
        a0 += s0a + s0b;
        a1 += s1a + s1b;
        // activations: c0 is gate 0/1 (sigmoid); c1 is gate 2 (tanh) for t<256,
        // gate 3 (sigmoid) otherwise. t<256 boundary is wave-uniform.
        gl[c0] = sigm_f(a0);
        gl[c1] = (t < 256) ? tanh_f(a1) : sigm_f(a1);
        __syncthreads();
        if (t < 256) {
            float f  = gl[t];
            float ii = gl[256 + t];
            float gg = gl[512 + t];
            float o  = gl[768 + t];
            float c  = fmaf(f, creg, ii * gg);
            creg = c;
            float h = o * tanh_f(c);
            hl2[t] = (_Float16)h;
            out[((size_t)(t0 + tt) * BATCH + b) * HID + t] = h;
        }
        __syncthreads();
    }
    if (t < 256) {
        hstate[b * HID + t] = (float)hl2[t];
        cstate[b * HID + t] = creg;
    }
}

// ---------------- tail: final hx, cx ------------------------------------------
__global__ void tail_kernel(const float* __restrict__ hstate,
                            const float* __restrict__ cstate, float* __restrict__ out) {
    int b = blockIdx.x, r = threadIdx.x;
    size_t base = (size_t)T_SEQ * BATCH * HID;
    out[base + b * HID + r] = hstate[b * HID + r];
    out[base + (size_t)BATCH * HID + b * HID + r] = cstate[b * HID + r];
}

extern "C" void kernel_launch(void* const* d_in, const int* in_sizes, int n_in,
                              void* d_out, int out_size, void* d_ws, size_t ws_size,
                              hipStream_t stream) {
    (void)in_sizes; (void)n_in; (void)out_size;
    const float* X  = (const float*)d_in[0];
    const float* Wf = (const float*)d_in[1];
    const float* bf = (const float*)d_in[2];
    const float* Wi = (const float*)d_in[3];
    const float* bi = (const float*)d_in[4];
    const float* Wg = (const float*)d_in[5];
    const float* bg = (const float*)d_in[6];
    const float* Wo = (const float*)d_in[7];
    const float* bo = (const float*)d_in[8];
    float* out = (float*)d_out;
    char*  ws  = (char*)d_ws;

    const size_t MB = 1 << 20, KB = 1 << 10;
    float*    wx4    = (float*)(ws);                          // 1 MB
    _Float16* wzh    = (_Float16*)(ws + MB);                  // 512 KB
    float*    bias4  = (float*)(ws + MB + 512 * KB);          // 4 KB
    float*    hstate = (float*)(ws + MB + 576 * KB);          // 64 KB
    float*    cstate = (float*)(ws + MB + 640 * KB);          // 64 KB
    float*    xproj  = (float*)(ws + 2 * MB);

    size_t fixed = 2 * MB;
    int Tc = 1024;
    while (Tc > 16 && fixed + (size_t)Tc * BATCH * NG * 4 > ws_size) Tc >>= 1;

    pack_kernel<<<256, 1024, 0, stream>>>(Wf, bf, Wi, bi, Wg, bg, Wo, bo,
                                          wx4, wzh, bias4, hstate, cstate);
    for (int t0 = 0; t0 < T_SEQ; t0 += Tc) {
        xproj_kernel<<<Tc * BATCH / 16, 256, 0, stream>>>(
            X + (size_t)t0 * BATCH * DIM, wx4, bias4, xproj);
        lstm_step_kernel<<<BATCH, 512, 0, stream>>>(
            xproj, wzh, hstate, cstate, out, t0, Tc);
    }
    tail_kernel<<<BATCH, HID, 0, stream>>>(hstate, cstate, out);
}